// Round 5
// baseline (234.780 us; speedup 1.0000x reference)
//
#include <hip/hip_runtime.h>

typedef unsigned short u16;
typedef unsigned int   u32;
typedef __attribute__((ext_vector_type(8)))  __bf16 bf16x8;
typedef __attribute__((ext_vector_type(16))) float  f32x16;
typedef __attribute__((ext_vector_type(4)))  float  fl4;
typedef __attribute__((ext_vector_type(4)))  u16    u16x4;
typedef __attribute__((ext_vector_type(4)))  u32    u32x4;

#define NB 16
#define NT 2048
#define NC 1024
#define ND 128

__device__ __forceinline__ u16 f2bf(float f) {
  u32 u = __builtin_bit_cast(u32, f);
  u = (u + 0x7fffu + ((u >> 16) & 1u)) >> 16;
  return (u16)u;
}

__device__ __forceinline__ u32 pk2(float lo, float hi) {
  return (u32)f2bf(lo) | ((u32)f2bf(hi) << 16);
}

// -------------------- Kernel 0: W transpose prep --------------------
// Wt[kind][n][k] = W_kind[k][n] as bf16. 768 KB total, L2-resident after.
__global__ __launch_bounds__(256) void wprep_k(
    const float* __restrict__ Wq, const float* __restrict__ Wk,
    const float* __restrict__ Wv, u16* __restrict__ wt)
{
  const int kind = blockIdx.x;
  const int nb   = blockIdx.y;          // 0..7
  const float* __restrict__ W = (kind == 0) ? Wq : (kind == 1) ? Wk : Wv;
  const int t = threadIdx.x;
  const int n  = nb * 16 + (t >> 4);
  const int k0 = (t & 15) * 64;
  u16* __restrict__ o = wt + ((size_t)kind * ND + n) * NC + k0;
  #pragma unroll 4
  for (int i = 0; i < 16; ++i) {
    u16x4 pk;
    #pragma unroll
    for (int j = 0; j < 4; ++j)
      pk[j] = f2bf(W[(size_t)(k0 + i * 4 + j) * ND + n]);
    *(u16x4*)(o + i * 4) = pk;
  }
}

// -------------------- Kernel 1: fused QKV projection (no LDS, no barriers) ----
// Grid 1024 x 256thr. Block = 32 x-rows; wave = 32 rows x 96 cols of the
// 384-wide fused [q|k|v] output. A-frags direct from x (f32->bf16 native cvt),
// B-frags direct from Wt (L1/L2-resident). TLP (16 waves/CU) hides latency.
// q scaled by log2e/sqrt(128); v stored transposed [B][D][T].
__global__ __launch_bounds__(256, 4) void qkv_fused_k(
    const float* __restrict__ x, const u16* __restrict__ wt,
    u16* __restrict__ qo, u16* __restrict__ ko, u16* __restrict__ vto)
{
  const int tile = blockIdx.x;          // 0..1023
  const int tid  = threadIdx.x;
  const int lane = tid & 63;
  const int wid  = tid >> 6;            // 0..3
  const int l31 = lane & 31, hi = lane >> 5;
  const int m0 = tile * 32;
  const int colbase = wid * 96;

  const float* __restrict__ xrow = x + (size_t)(m0 + l31) * NC + hi * 8;
  const u16*   __restrict__ wb   = wt + (size_t)colbase * NC;

  f32x16 acc[3] = {};

  #pragma unroll 8
  for (int ks = 0; ks < 64; ++ks) {
    const int k = ks * 16;
    // A fragment: row m0+l31, k + hi*8 .. +8 (f32 -> bf16, native cvt_pk)
    fl4 a0 = *(const fl4*)(xrow + k);
    fl4 a1 = *(const fl4*)(xrow + k + 4);
    bf16x8 a;
    a[0] = (__bf16)a0[0]; a[1] = (__bf16)a0[1]; a[2] = (__bf16)a0[2]; a[3] = (__bf16)a0[3];
    a[4] = (__bf16)a1[0]; a[5] = (__bf16)a1[1]; a[6] = (__bf16)a1[2]; a[7] = (__bf16)a1[3];
    #pragma unroll
    for (int fn = 0; fn < 3; ++fn) {
      bf16x8 b = *(const bf16x8*)(wb + (size_t)(fn * 32 + l31) * NC + k + hi * 8);
      acc[fn] = __builtin_amdgcn_mfma_f32_32x32x16_bf16(a, b, acc[fn], 0, 0, 0);
    }
  }

  const int bb = m0 >> 11;
  const int tb = m0 & (NT - 1);
  #pragma unroll
  for (int fn = 0; fn < 3; ++fn) {
    const int col  = colbase + fn * 32 + l31;
    const int kind = col >> 7;          // wave-uniform per fn (32-col blocks)
    const int d    = col & 127;
    if (kind < 2) {
      u16* __restrict__ o = (kind == 0) ? qo : ko;
      const float sc = (kind == 0) ? 0.12752539240377073f : 1.0f; // log2e/sqrt(128)
      #pragma unroll
      for (int r = 0; r < 16; ++r) {
        int row = m0 + (r & 3) + 8 * (r >> 2) + 4 * hi;
        o[(size_t)row * ND + d] = f2bf(acc[fn][r] * sc);
      }
    } else {
      #pragma unroll
      for (int g = 0; g < 4; ++g) {
        int t0 = tb + 8 * g + 4 * hi;   // 4 consecutive t
        u16x4 pk;
        #pragma unroll
        for (int j = 0; j < 4; ++j) pk[j] = f2bf(acc[fn][g * 4 + j]);
        *(u16x4*)(vto + ((size_t)bb * ND + d) * NT + t0) = pk;
      }
    }
  }
}

// -------------------- Kernel 2: flash attention --------------------
// One wave = one (batch, 32-row q-tile). Swapped QK^T (mfma(K,Q)) so each
// lane owns one q-row of S^T; softmax in-register; all cross-lane movement
// via __shfl_xor(·,32) partner exchange.
__global__ __launch_bounds__(256, 1) void attn_fwd_k(
    const u16* __restrict__ qw, const u16* __restrict__ kw,
    const u16* __restrict__ vtw, float* __restrict__ out)
{
  const int tid  = threadIdx.x;
  const int lane = tid & 63;
  const int wid  = tid >> 6;
  const int l31  = lane & 31;
  const int hi   = lane >> 5;

  // balanced heavy+light pairing over 1024 wave-tasks
  int pairIdx = blockIdx.x * 2 + (wid >> 1);          // 0..511
  int rho = (wid & 1) ? (1023 - pairIdx) : pairIdx;   // task rank
  int bb = rho & 15;
  int qi = 63 - (rho >> 4);                           // q-tile, heavy ranks first
  int q0 = qi * 32;
  int qrow = q0 + l31;

  const u16* __restrict__ qb = qw  + (size_t)bb * NT * ND;
  const u16* __restrict__ kb = kw  + (size_t)bb * NT * ND;
  const u16* __restrict__ vb = vtw + (size_t)bb * ND * NT;

  // Q fragments (B-operand): lane holds Q[q0+l31][s*16 + hi*8 + 0..7]
  bf16x8 qf[8];
  #pragma unroll
  for (int s = 0; s < 8; ++s)
    qf[s] = *(const bf16x8*)(qb + (size_t)qrow * ND + s * 16 + hi * 8);

  f32x16 of[4] = {};
  float m_run = -__builtin_inff();
  float l_run = 0.f;

  const int nsteps = (qi >> 1) + 1;
  for (int s = 0; s < nsteps; ++s) {
    const int kv0 = s * 64;
    const bool masked = (s == nsteps - 1);

    // K fragments (A-operand), both 32-row kv sub-tiles
    bf16x8 kf0[8], kf1[8];
    #pragma unroll
    for (int t = 0; t < 8; ++t) {
      kf0[t] = *(const bf16x8*)(kb + (size_t)(kv0 + l31) * ND + t * 16 + hi * 8);
      kf1[t] = *(const bf16x8*)(kb + (size_t)(kv0 + 32 + l31) * ND + t * 16 + hi * 8);
    }
    f32x16 st0 = {}, st1 = {};
    #pragma unroll
    for (int t = 0; t < 8; ++t) {
      st0 = __builtin_amdgcn_mfma_f32_32x32x16_bf16(kf0[t], qf[t], st0, 0, 0, 0);
      st1 = __builtin_amdgcn_mfma_f32_32x32x16_bf16(kf1[t], qf[t], st1, 0, 0, 0);
    }
    // V^T fragments issued early so latency hides under softmax
    bf16x8 vf[4][4];
    #pragma unroll
    for (int dt = 0; dt < 4; ++dt)
      #pragma unroll
      for (int ks = 0; ks < 4; ++ks)
        vf[dt][ks] = *(const bf16x8*)(vb + (size_t)(dt * 32 + l31) * NT + kv0 + ks * 16 + hi * 8);

    if (masked) {
      #pragma unroll
      for (int r = 0; r < 16; ++r) {
        int crow = (r & 3) + 8 * (r >> 2) + 4 * hi;
        st0[r] = (kv0 + crow      <= qrow) ? st0[r] : -1e30f;
        st1[r] = (kv0 + 32 + crow <= qrow) ? st1[r] : -1e30f;
      }
    }

    // row max: 32 in-lane values + partner half via shfl_xor
    float pmax = -1e30f;
    #pragma unroll
    for (int r = 0; r < 16; ++r) pmax = fmaxf(pmax, fmaxf(st0[r], st1[r]));
    pmax = fmaxf(pmax, __shfl_xor(pmax, 32, 64));

    const bool no_rescale = (pmax <= m_run);
    const float m_new = fmaxf(m_run, pmax);
    const float fac = __builtin_amdgcn_exp2f(m_run - m_new);
    float rsum = 0.f;
    #pragma unroll
    for (int r = 0; r < 16; ++r) {
      st0[r] = __builtin_amdgcn_exp2f(st0[r] - m_new);
      st1[r] = __builtin_amdgcn_exp2f(st1[r] - m_new);
      rsum += st0[r] + st1[r];
    }
    rsum += __shfl_xor(rsum, 32, 64);
    l_run = l_run * fac + rsum;
    m_run = m_new;

    if (!__all(no_rescale)) {
      #pragma unroll
      for (int r = 0; r < 16; ++r) {
        float fr = __shfl(fac, (r & 3) + 8 * (r >> 2) + 4 * hi, 64);
        #pragma unroll
        for (int dt = 0; dt < 4; ++dt) of[dt][r] *= fr;
      }
    }

    // P (f32, D-layout) -> bf16 A-operand fragments.
    u32x4 pa[4];
    #pragma unroll
    for (int g = 0; g < 4; ++g) {
      const float* sp = (g < 2) ? (const float*)&st0 : (const float*)&st1;
      const int o8 = (g & 1) * 8;
      u32 a0 = pk2(sp[o8 + 0], sp[o8 + 1]);
      u32 a1 = pk2(sp[o8 + 2], sp[o8 + 3]);
      u32 b0 = pk2(sp[o8 + 4], sp[o8 + 5]);
      u32 b1 = pk2(sp[o8 + 6], sp[o8 + 7]);
      u32 ta0 = __shfl_xor(a0, 32, 64);
      u32 ta1 = __shfl_xor(a1, 32, 64);
      u32 tb0 = __shfl_xor(b0, 32, 64);
      u32 tb1 = __shfl_xor(b1, 32, 64);
      pa[g][0] = hi ? tb0 : a0;
      pa[g][1] = hi ? tb1 : a1;
      pa[g][2] = hi ? b0  : ta0;
      pa[g][3] = hi ? b1  : ta1;
    }

    #pragma unroll
    for (int ks = 0; ks < 4; ++ks) {
      bf16x8 paf = __builtin_bit_cast(bf16x8, pa[ks]);
      #pragma unroll
      for (int dt = 0; dt < 4; ++dt)
        of[dt] = __builtin_amdgcn_mfma_f32_32x32x16_bf16(paf, vf[dt][ks], of[dt], 0, 0, 0);
    }
  }

  const float rl = 1.0f / l_run;
  #pragma unroll
  for (int r = 0; r < 16; ++r) {
    int crow = (r & 3) + 8 * (r >> 2) + 4 * hi;
    float lr = __shfl(rl, crow, 64);
    #pragma unroll
    for (int dt = 0; dt < 4; ++dt)
      out[((size_t)(bb * NT + q0 + crow)) * ND + dt * 32 + l31] = of[dt][r] * lr;
  }
}

extern "C" void kernel_launch(void* const* d_in, const int* in_sizes, int n_in,
                              void* d_out, int out_size, void* d_ws, size_t ws_size,
                              hipStream_t stream) {
  (void)in_sizes; (void)n_in; (void)out_size; (void)ws_size;
  const float* x  = (const float*)d_in[0];
  const float* Wq = (const float*)d_in[1];
  const float* Wk = (const float*)d_in[2];
  const float* Wv = (const float*)d_in[3];
  float* out = (float*)d_out;

  u16* qws  = (u16*)d_ws;                               // [B][T][D] bf16
  u16* kws  = qws + (size_t)NB * NT * ND;               // [B][T][D] bf16
  u16* vtws = kws + (size_t)NB * NT * ND;               // [B][D][T] bf16
  u16* wtws = vtws + (size_t)NB * ND * NT;              // [3][128][1024] bf16

  wprep_k<<<dim3(3, 8), dim3(256), 0, stream>>>(Wq, Wk, Wv, wtws);
  qkv_fused_k<<<dim3(1024), dim3(256), 0, stream>>>(x, wtws, qws, kws, vtws);
  attn_fwd_k<<<dim3(256), dim3(256), 0, stream>>>(qws, kws, vtws, out);
}

// Round 6
// 169.626 us; speedup vs baseline: 1.3841x; 1.3841x over previous
//
#include <hip/hip_runtime.h>

typedef unsigned short u16;
typedef unsigned int   u32;
typedef __attribute__((ext_vector_type(8)))  __bf16 bf16x8;
typedef __attribute__((ext_vector_type(16))) float  f32x16;
typedef __attribute__((ext_vector_type(4)))  float  fl4;
typedef __attribute__((ext_vector_type(4)))  u16    u16x4;
typedef __attribute__((ext_vector_type(4)))  u32    u32x4;

#define NB 16
#define NT 2048
#define NC 1024
#define ND 128

// Fragment-order layout (shared by qkv epilogue and attn loads):
//   frag F[t32][ds][lane][8] bf16, 1KB per (t32,ds):
//     element (row m, col d): t32=m>>5, ds=d>>4, lane=(m&31)+32*((d>>3)&1), j=d&7
//   q/k per batch: 64 t32-blocks x 8 ds x 512 u16 (stride 4096 u16 per t32)
//   v  per batch: c=t>>4 (128 blocks) x dt=d>>5 (4) x 512 u16:
//     element (t,d): lane=(d&31)+32*((t>>3)&1), j=t&7

__device__ __forceinline__ u16 f2bf(float f) {
  u32 u = __builtin_bit_cast(u32, f);
  u = (u + 0x7fffu + ((u >> 16) & 1u)) >> 16;
  return (u16)u;
}

__device__ __forceinline__ u32 pk2(float lo, float hi) {
  return (u32)f2bf(lo) | ((u32)f2bf(hi) << 16);
}

// -------------------- Kernel 0: W -> fragment-order wf --------------------
// wf[cb 0..11][ks 0..63][lane][8]: value = W_{cb>>2}[k=ks*16+(lane>>5)*8+j][(cb&3)*32+(lane&31)]
__global__ __launch_bounds__(256) void wprep_k(
    const float* __restrict__ Wq, const float* __restrict__ Wk,
    const float* __restrict__ Wv, u16* __restrict__ wf)
{
  const int cb   = blockIdx.x;          // 0..11
  const int kind = cb >> 2;
  const float* __restrict__ W = (kind == 0) ? Wq : (kind == 1) ? Wk : Wv;
  const int lane = threadIdx.x & 63;
  const int ksq  = threadIdx.x >> 6;    // 0..3
  const int l31 = lane & 31, hi = lane >> 5;
  const int d = (cb & 3) * 32 + l31;
  u16* __restrict__ o = wf + (size_t)cb * 64 * 512;
  #pragma unroll 4
  for (int ii = 0; ii < 16; ++ii) {
    int ks = ksq * 16 + ii;
    int k  = ks * 16 + hi * 8;
    u16x4 p0, p1;
    #pragma unroll
    for (int j = 0; j < 4; ++j) p0[j] = f2bf(W[(size_t)(k + j) * ND + d]);
    #pragma unroll
    for (int j = 0; j < 4; ++j) p1[j] = f2bf(W[(size_t)(k + 4 + j) * ND + d]);
    u16* dst = o + ((size_t)ks * 64 + lane) * 8;
    *(u16x4*)dst = p0;
    *(u16x4*)(dst + 4) = p1;
  }
}

// -------------------- Kernel 1: fused QKV projection --------------------
// Block = 32 x-rows, 4 waves (wave = 32 rows x 96 of the 384 fused cols).
// x-tile staged ONCE into LDS in A-frag order (1 barrier/kernel); all hot-loop
// loads wave-contiguous. Outputs written in fragment order for attn.
__global__ __launch_bounds__(256, 2) void qkv_fused_k(
    const float* __restrict__ x, const u16* __restrict__ wf,
    u16* __restrict__ qf, u16* __restrict__ kf, u16* __restrict__ vf)
{
  const int tile = blockIdx.x;          // 0..1023
  const int tid  = threadIdx.x;
  const int lane = tid & 63;
  const int wid  = tid >> 6;            // 0..3
  const int l31 = lane & 31, hi = lane >> 5;
  const int m0 = tile * 32;

  __shared__ u16 Af[64 * 512];          // A-frag order: [(ks*64+lane)*8+j], 64KB

  // ---- stage: x[m0..m0+32) x K=1024, f32 -> bf16, frag-order ----
  {
    const int row = tid >> 3;           // 0..31
    const int kb  = (tid & 7) * 4;
    const float* __restrict__ xr = x + (size_t)(m0 + row) * NC;
    #pragma unroll 8
    for (int i = 0; i < 32; ++i) {
      int k = i * 32 + kb;
      fl4 v = *(const fl4*)(xr + k);
      int ks = k >> 4, hik = (k >> 3) & 1, j = k & 7;   // j in {0,4}
      u16x4 pk;
      pk[0] = f2bf(v[0]); pk[1] = f2bf(v[1]); pk[2] = f2bf(v[2]); pk[3] = f2bf(v[3]);
      *(u16x4*)&Af[((size_t)ks * 64 + row + 32 * hik) * 8 + j] = pk;
    }
  }
  __syncthreads();

  f32x16 acc[3] = {};
  const int cb0 = wid * 3;

  #pragma unroll 4
  for (int ks = 0; ks < 64; ++ks) {
    bf16x8 a = *(const bf16x8*)&Af[(ks * 64 + lane) * 8];
    #pragma unroll
    for (int fn = 0; fn < 3; ++fn) {
      bf16x8 b = *(const bf16x8*)(wf + (((size_t)(cb0 + fn) * 64 + ks) * 64 + lane) * 8);
      acc[fn] = __builtin_amdgcn_mfma_f32_32x32x16_bf16(a, b, acc[fn], 0, 0, 0);
    }
  }

  // ---- epilogue: write frag-order q/k/v ----
  #pragma unroll
  for (int fn = 0; fn < 3; ++fn) {
    const int colb = wid * 96 + fn * 32;       // wave-uniform
    const int kind = colb >> 7;
    const int d    = (colb + l31) & 127;
    if (kind < 2) {
      u16* __restrict__ o = kind ? kf : qf;
      const float sc = kind ? 1.0f : 0.12752539240377073f; // log2e/sqrt(128)
      const int ds = d >> 4, b3 = (d >> 3) & 1, j = d & 7;
      u16* __restrict__ base = o + ((size_t)tile * 8 + ds) * 512 + 32 * b3 * 8 + j;
      #pragma unroll
      for (int r = 0; r < 16; ++r) {
        int crow = (r & 3) + 8 * (r >> 2) + 4 * hi;
        base[crow * 8] = f2bf(acc[fn][r] * sc);
      }
    } else {
      const int dt = d >> 5;
      #pragma unroll
      for (int g = 0; g < 4; ++g) {
        int c16   = tile * 2 + (g >> 1);
        int lanep = l31 + 32 * (g & 1);
        u16x4 pk;
        #pragma unroll
        for (int jj = 0; jj < 4; ++jj) pk[jj] = f2bf(acc[fn][g * 4 + jj]);
        *(u16x4*)(vf + (((size_t)c16 * 4 + dt) * 64 + lanep) * 8 + 4 * hi) = pk;
      }
    }
  }
}

// -------------------- Kernel 2: flash attention --------------------
// One wave = one (batch, 32-row q-tile). All fragment loads are contiguous
// 1KB wave loads from frag-order q/k/v. Swapped QK^T, in-register softmax.
__global__ __launch_bounds__(256, 1) void attn_fwd_k(
    const u16* __restrict__ qw, const u16* __restrict__ kw,
    const u16* __restrict__ vw, float* __restrict__ out)
{
  const int tid  = threadIdx.x;
  const int lane = tid & 63;
  const int wid  = tid >> 6;
  const int l31  = lane & 31;
  const int hi   = lane >> 5;

  // heavy+light pairing; adjacent ranks share batch+adjacent qi (KV L1 reuse)
  int pairIdx = blockIdx.x * 2 + (wid >> 1);          // 0..511
  int rho = (wid & 1) ? (1023 - pairIdx) : pairIdx;   // task rank
  int bb = rho >> 6;
  int qi = 63 - (rho & 63);                           // heavy ranks first
  int q0 = qi * 32;
  int qrow = q0 + l31;

  const u16* __restrict__ qb = qw + ((size_t)bb * 64 + qi) * 4096;
  const u16* __restrict__ kb = kw + (size_t)bb * 64 * 4096;
  const u16* __restrict__ vb = vw + (size_t)bb * 128 * 2048;

  bf16x8 qfr[8];
  #pragma unroll
  for (int s = 0; s < 8; ++s)
    qfr[s] = *(const bf16x8*)(qb + ((size_t)s * 64 + lane) * 8);

  f32x16 of[4] = {};
  float m_run = -__builtin_inff();
  float l_run = 0.f;

  const int nsteps = (qi >> 1) + 1;
  for (int s = 0; s < nsteps; ++s) {
    const int kv0 = s * 64;
    const bool masked = (s == nsteps - 1);

    bf16x8 kf0[8], kf1[8];
    #pragma unroll
    for (int t = 0; t < 8; ++t) {
      kf0[t] = *(const bf16x8*)(kb + (((size_t)(2 * s) * 8 + t) * 64 + lane) * 8);
      kf1[t] = *(const bf16x8*)(kb + (((size_t)(2 * s + 1) * 8 + t) * 64 + lane) * 8);
    }
    f32x16 st0 = {}, st1 = {};
    #pragma unroll
    for (int t = 0; t < 8; ++t) {
      st0 = __builtin_amdgcn_mfma_f32_32x32x16_bf16(kf0[t], qfr[t], st0, 0, 0, 0);
      st1 = __builtin_amdgcn_mfma_f32_32x32x16_bf16(kf1[t], qfr[t], st1, 0, 0, 0);
    }
    // V fragments (frag-order, contiguous) issued early
    bf16x8 vfr[4][4];
    #pragma unroll
    for (int ks = 0; ks < 4; ++ks)
      #pragma unroll
      for (int dt = 0; dt < 4; ++dt)
        vfr[dt][ks] = *(const bf16x8*)(vb + (((size_t)((kv0 >> 4) + ks) * 4 + dt) * 64 + lane) * 8);

    if (masked) {
      #pragma unroll
      for (int r = 0; r < 16; ++r) {
        int crow = (r & 3) + 8 * (r >> 2) + 4 * hi;
        st0[r] = (kv0 + crow      <= qrow) ? st0[r] : -1e30f;
        st1[r] = (kv0 + 32 + crow <= qrow) ? st1[r] : -1e30f;
      }
    }

    float pmax = -1e30f;
    #pragma unroll
    for (int r = 0; r < 16; ++r) pmax = fmaxf(pmax, fmaxf(st0[r], st1[r]));
    pmax = fmaxf(pmax, __shfl_xor(pmax, 32, 64));

    const bool no_rescale = (pmax <= m_run);
    const float m_new = fmaxf(m_run, pmax);
    const float fac = __builtin_amdgcn_exp2f(m_run - m_new);
    float rsum = 0.f;
    #pragma unroll
    for (int r = 0; r < 16; ++r) {
      st0[r] = __builtin_amdgcn_exp2f(st0[r] - m_new);
      st1[r] = __builtin_amdgcn_exp2f(st1[r] - m_new);
      rsum += st0[r] + st1[r];
    }
    rsum += __shfl_xor(rsum, 32, 64);
    l_run = l_run * fac + rsum;
    m_run = m_new;

    if (!__all(no_rescale)) {
      #pragma unroll
      for (int r = 0; r < 16; ++r) {
        float fr = __shfl(fac, (r & 3) + 8 * (r >> 2) + 4 * hi, 64);
        #pragma unroll
        for (int dt = 0; dt < 4; ++dt) of[dt][r] *= fr;
      }
    }

    // P (f32, D-layout) -> bf16 A-operand fragments via shfl_xor(32)
    u32x4 pa[4];
    #pragma unroll
    for (int g = 0; g < 4; ++g) {
      const float* sp = (g < 2) ? (const float*)&st0 : (const float*)&st1;
      const int o8 = (g & 1) * 8;
      u32 a0 = pk2(sp[o8 + 0], sp[o8 + 1]);
      u32 a1 = pk2(sp[o8 + 2], sp[o8 + 3]);
      u32 b0 = pk2(sp[o8 + 4], sp[o8 + 5]);
      u32 b1 = pk2(sp[o8 + 6], sp[o8 + 7]);
      u32 ta0 = __shfl_xor(a0, 32, 64);
      u32 ta1 = __shfl_xor(a1, 32, 64);
      u32 tb0 = __shfl_xor(b0, 32, 64);
      u32 tb1 = __shfl_xor(b1, 32, 64);
      pa[g][0] = hi ? tb0 : a0;
      pa[g][1] = hi ? tb1 : a1;
      pa[g][2] = hi ? b0  : ta0;
      pa[g][3] = hi ? b1  : ta1;
    }

    #pragma unroll
    for (int ks = 0; ks < 4; ++ks) {
      bf16x8 paf = __builtin_bit_cast(bf16x8, pa[ks]);
      #pragma unroll
      for (int dt = 0; dt < 4; ++dt)
        of[dt] = __builtin_amdgcn_mfma_f32_32x32x16_bf16(paf, vfr[dt][ks], of[dt], 0, 0, 0);
    }
  }

  const float rl = 1.0f / l_run;
  #pragma unroll
  for (int r = 0; r < 16; ++r) {
    int crow = (r & 3) + 8 * (r >> 2) + 4 * hi;
    float lr = __shfl(rl, crow, 64);
    #pragma unroll
    for (int dt = 0; dt < 4; ++dt)
      out[((size_t)(bb * NT + q0 + crow)) * ND + dt * 32 + l31] = of[dt][r] * lr;
  }
}

extern "C" void kernel_launch(void* const* d_in, const int* in_sizes, int n_in,
                              void* d_out, int out_size, void* d_ws, size_t ws_size,
                              hipStream_t stream) {
  (void)in_sizes; (void)n_in; (void)out_size; (void)ws_size;
  const float* x  = (const float*)d_in[0];
  const float* Wq = (const float*)d_in[1];
  const float* Wk = (const float*)d_in[2];
  const float* Wv = (const float*)d_in[3];
  float* out = (float*)d_out;

  u16* qws = (u16*)d_ws;                                // frag-order q: 8 MB
  u16* kws = qws + (size_t)NB * NT * ND;                // frag-order k: 8 MB
  u16* vws = kws + (size_t)NB * NT * ND;                // frag-order v: 8 MB
  u16* wfs = vws + (size_t)NB * NT * ND;                // frag-order W: 768 KB

  wprep_k<<<dim3(12), dim3(256), 0, stream>>>(Wq, Wk, Wv, wfs);
  qkv_fused_k<<<dim3(1024), dim3(256), 0, stream>>>(x, wfs, qws, kws, vws);
  attn_fwd_k<<<dim3(256), dim3(256), 0, stream>>>(qws, kws, vws, out);
}

// Round 7
// 119.068 us; speedup vs baseline: 1.9718x; 1.4246x over previous
//
#include <hip/hip_runtime.h>

typedef unsigned short u16;
typedef unsigned int   u32;
typedef __attribute__((ext_vector_type(8)))  __bf16 bf16x8;
typedef __attribute__((ext_vector_type(16))) float  f32x16;
typedef __attribute__((ext_vector_type(4)))  float  fl4;
typedef __attribute__((ext_vector_type(4)))  u16    u16x4;
typedef __attribute__((ext_vector_type(4)))  u32    u32x4;

#define NB 16
#define NT 2048
#define NC 1024
#define ND 128

// Fragment-order layouts (unchanged from r6):
//   q/k per batch: [t32 0..63][ds 0..7][lane][8]  (1KB per (t32,ds))
//   v  per batch: [c=t>>4 0..127][dt=d>>5 0..3][lane=(d&31)+32*((t>>3)&1)][j=t&7]
//   wf: [cb 0..11][ks 0..63][lane][8] : W_{cb>>2}[k=ks*16+(lane>>5)*8+j][(cb&3)*32+(lane&31)]

__device__ __forceinline__ u16 f2bf(float f) {
  u32 u = __builtin_bit_cast(u32, f);
  u = (u + 0x7fffu + ((u >> 16) & 1u)) >> 16;
  return (u16)u;
}

__device__ __forceinline__ u32 pk2(float lo, float hi) {
  return (u32)f2bf(lo) | ((u32)f2bf(hi) << 16);
}

// -------------------- Kernel 0: W -> fragment-order wf --------------------
__global__ __launch_bounds__(256) void wprep_k(
    const float* __restrict__ Wq, const float* __restrict__ Wk,
    const float* __restrict__ Wv, u16* __restrict__ wf)
{
  const int cb   = blockIdx.x;          // 0..11
  const int kind = cb >> 2;
  const float* __restrict__ W = (kind == 0) ? Wq : (kind == 1) ? Wk : Wv;
  const int lane = threadIdx.x & 63;
  const int ksq  = threadIdx.x >> 6;    // 0..3
  const int l31 = lane & 31, hi = lane >> 5;
  const int d = (cb & 3) * 32 + l31;
  u16* __restrict__ o = wf + (size_t)cb * 64 * 512;
  #pragma unroll 4
  for (int ii = 0; ii < 16; ++ii) {
    int ks = ksq * 16 + ii;
    int k  = ks * 16 + hi * 8;
    u16x4 p0, p1;
    #pragma unroll
    for (int j = 0; j < 4; ++j) p0[j] = f2bf(W[(size_t)(k + j) * ND + d]);
    #pragma unroll
    for (int j = 0; j < 4; ++j) p1[j] = f2bf(W[(size_t)(k + 4 + j) * ND + d]);
    u16* dst = o + ((size_t)ks * 64 + lane) * 8;
    *(u16x4*)dst = p0;
    *(u16x4*)(dst + 4) = p1;
  }
}

// -------------------- Kernel 1: fused QKV projection --------------------
// 512 blocks (128 rows x 192-col half) x 512 thr (8 waves = 4r x 2c).
// Double-buffered frag-order LDS (A 2x16KB, B 2x24KB = 80KB -> 2 blocks/CU).
// Per K-step: issue next loads -> compute current (contiguous ds_read_b128,
// conflict-free) -> cvt+write next -> 1 barrier.  q scaled by log2e/sqrt(128);
// outputs written in fragment order for attn.
__global__ __launch_bounds__(512, 4) void qkv_fused_k(
    const float* __restrict__ x, const u16* __restrict__ wf,
    u16* __restrict__ qf, u16* __restrict__ kf, u16* __restrict__ vf)
{
  const int blk  = blockIdx.x;          // 0..511
  const int brow = blk >> 1;            // 128-row tile
  const int h    = blk & 1;             // 192-col half
  const int tid  = threadIdx.x;
  const int lane = tid & 63;
  const int wid  = tid >> 6;            // 0..7
  const int rw = wid & 3, cw = wid >> 2;
  const int l31 = lane & 31, hi = lane >> 5;
  const int m0 = brow * 128;
  const int cbg0 = h * 6;

  __shared__ u16 Ab[2][16 * 512];       // frag-order: addr16B = (ks*4+rb)*64+lane
  __shared__ u16 Bb[2][24 * 512];       // frag-order: addr16B = (cb6*4+ks)*64+lane

  // A staging map: thread -> (row = tid&127, chunks cc = ac, ac+4), 32B f32 each
  const int arow = tid & 127;
  const int ac   = tid >> 7;            // 0..3
  const float* __restrict__ xr = x + (size_t)(m0 + arow) * NC;
  const int ad0 = ((ac >> 1) * 4 + (arow >> 5)) * 64 + (arow & 31) + 32 * (ac & 1);
  const int ac4 = ac + 4;
  const int ad1 = ((ac4 >> 1) * 4 + (arow >> 5)) * 64 + (arow & 31) + 32 * (ac4 & 1);

  fl4 xa, xb, xc, xd;                   // pending A (f32)
  bf16x8 bw[3];                         // pending B

  auto issueA = [&](int bk) {
    const float* p = xr + bk * 64 + ac * 8;
    xa = *(const fl4*)(p);
    xb = *(const fl4*)(p + 4);
    xc = *(const fl4*)(p + 32);
    xd = *(const fl4*)(p + 36);
  };
  auto issueB = [&](int bk) {
    #pragma unroll
    for (int i = 0; i < 3; ++i) {
      int idx = i * 512 + tid;
      int cb6 = idx >> 8, ks = (idx >> 6) & 3;
      bw[i] = *(const bf16x8*)(wf + (((size_t)(cbg0 + cb6) * 64 + bk * 4 + ks) * 64 + (idx & 63)) * 8);
    }
  };
  auto writeA = [&](int buf) {
    bf16x8 v0, v1;
    v0[0]=(__bf16)xa[0]; v0[1]=(__bf16)xa[1]; v0[2]=(__bf16)xa[2]; v0[3]=(__bf16)xa[3];
    v0[4]=(__bf16)xb[0]; v0[5]=(__bf16)xb[1]; v0[6]=(__bf16)xb[2]; v0[7]=(__bf16)xb[3];
    v1[0]=(__bf16)xc[0]; v1[1]=(__bf16)xc[1]; v1[2]=(__bf16)xc[2]; v1[3]=(__bf16)xc[3];
    v1[4]=(__bf16)xd[0]; v1[5]=(__bf16)xd[1]; v1[6]=(__bf16)xd[2]; v1[7]=(__bf16)xd[3];
    *(bf16x8*)&Ab[buf][(size_t)ad0 * 8] = v0;
    *(bf16x8*)&Ab[buf][(size_t)ad1 * 8] = v1;
  };
  auto writeB = [&](int buf) {
    #pragma unroll
    for (int i = 0; i < 3; ++i)
      *(bf16x8*)&Bb[buf][((size_t)i * 512 + tid) * 8] = bw[i];
  };

  f32x16 acc[3] = {};

  issueA(0); issueB(0);
  writeA(0); writeB(0);
  __syncthreads();

  for (int bk = 0; bk < 16; ++bk) {
    const int cur = bk & 1;
    if (bk < 15) { issueA(bk + 1); issueB(bk + 1); }
    #pragma unroll
    for (int ks = 0; ks < 4; ++ks) {
      bf16x8 a = *(const bf16x8*)&Ab[cur][((size_t)(ks * 4 + rw) * 64 + lane) * 8];
      #pragma unroll
      for (int cb = 0; cb < 3; ++cb) {
        bf16x8 b = *(const bf16x8*)&Bb[cur][((size_t)((cw * 3 + cb) * 4 + ks) * 64 + lane) * 8];
        acc[cb] = __builtin_amdgcn_mfma_f32_32x32x16_bf16(a, b, acc[cb], 0, 0, 0);
      }
    }
    if (bk < 15) { writeA(cur ^ 1); writeB(cur ^ 1); }
    __syncthreads();
  }

  // ---- epilogue: frag-order q/k/v writes ----
  const int t32 = brow * 4 + rw;
  #pragma unroll
  for (int cb = 0; cb < 3; ++cb) {
    const int colb = h * 192 + cw * 96 + cb * 32;  // wave-uniform
    const int kind = colb >> 7;
    const int d    = (colb & 127) + l31;
    if (kind < 2) {
      u16* __restrict__ o = kind ? kf : qf;
      const float sc = kind ? 1.0f : 0.12752539240377073f; // log2e/sqrt(128)
      const int ds = d >> 4, b3 = (d >> 3) & 1, j = d & 7;
      u16* __restrict__ base = o + ((size_t)t32 * 8 + ds) * 512 + 32 * b3 * 8 + j;
      #pragma unroll
      for (int r = 0; r < 16; ++r) {
        int crow = (r & 3) + 8 * (r >> 2) + 4 * hi;
        base[crow * 8] = f2bf(acc[cb][r] * sc);
      }
    } else {
      const int dt = (d & 127) >> 5;
      #pragma unroll
      for (int g = 0; g < 4; ++g) {
        int c16   = t32 * 2 + (g >> 1);
        int lanep = l31 + 32 * (g & 1);
        u16x4 pk;
        #pragma unroll
        for (int jj = 0; jj < 4; ++jj) pk[jj] = f2bf(acc[cb][g * 4 + jj]);
        *(u16x4*)(vf + (((size_t)c16 * 4 + dt) * 64 + lanep) * 8 + 4 * hi) = pk;
      }
    }
  }
}

// -------------------- Kernel 2: flash attention (KV-split x2) --------------------
// 1024 blocks x 2 waves; both waves share one (batch, 32-row q-tile), wave w
// handles kv steps s == w (mod 2). Partials merged via LDS (flash combine).
__global__ __launch_bounds__(128, 2) void attn_fwd_k(
    const u16* __restrict__ qw, const u16* __restrict__ kw,
    const u16* __restrict__ vw, float* __restrict__ out)
{
  const int tid  = threadIdx.x;
  const int lane = tid & 63;
  const int w    = tid >> 6;            // 0/1 split
  const int l31  = lane & 31;
  const int hi   = lane >> 5;

  // bijective (bb,qi) map spreading heavy qi across CUs
  const int c  = blockIdx.x;
  const int bb = (c >> 6) & 15;
  const int qi = ((c & 63) + ((c >> 8) << 4)) & 63;
  const int q0 = qi * 32;
  const int qrow = q0 + l31;

  const u16* __restrict__ qb = qw + ((size_t)bb * 64 + qi) * 4096;
  const u16* __restrict__ kb = kw + (size_t)bb * 64 * 4096;
  const u16* __restrict__ vb = vw + (size_t)bb * 128 * 2048;

  __shared__ float ofs[64][64];         // [dt*16+r][lane]
  __shared__ float mls[2][64];

  bf16x8 qfr[8];
  #pragma unroll
  for (int s = 0; s < 8; ++s)
    qfr[s] = *(const bf16x8*)(qb + ((size_t)s * 64 + lane) * 8);

  f32x16 of[4] = {};
  float m_run = -__builtin_inff();
  float l_run = 0.f;

  const int nsteps = (qi >> 1) + 1;
  for (int s = w; s < nsteps; s += 2) {
    const int kv0 = s * 64;
    const bool masked = (s == nsteps - 1);

    bf16x8 kf0[8], kf1[8];
    #pragma unroll
    for (int t = 0; t < 8; ++t) {
      kf0[t] = *(const bf16x8*)(kb + (((size_t)(2 * s) * 8 + t) * 64 + lane) * 8);
      kf1[t] = *(const bf16x8*)(kb + (((size_t)(2 * s + 1) * 8 + t) * 64 + lane) * 8);
    }
    f32x16 st0 = {}, st1 = {};
    #pragma unroll
    for (int t = 0; t < 8; ++t) {
      st0 = __builtin_amdgcn_mfma_f32_32x32x16_bf16(kf0[t], qfr[t], st0, 0, 0, 0);
      st1 = __builtin_amdgcn_mfma_f32_32x32x16_bf16(kf1[t], qfr[t], st1, 0, 0, 0);
    }
    bf16x8 vfr[4][4];
    #pragma unroll
    for (int ks = 0; ks < 4; ++ks)
      #pragma unroll
      for (int dt = 0; dt < 4; ++dt)
        vfr[dt][ks] = *(const bf16x8*)(vb + (((size_t)((kv0 >> 4) + ks) * 4 + dt) * 64 + lane) * 8);

    if (masked) {
      #pragma unroll
      for (int r = 0; r < 16; ++r) {
        int crow = (r & 3) + 8 * (r >> 2) + 4 * hi;
        st0[r] = (kv0 + crow      <= qrow) ? st0[r] : -1e30f;
        st1[r] = (kv0 + 32 + crow <= qrow) ? st1[r] : -1e30f;
      }
    }

    float pmax = -1e30f;
    #pragma unroll
    for (int r = 0; r < 16; ++r) pmax = fmaxf(pmax, fmaxf(st0[r], st1[r]));
    pmax = fmaxf(pmax, __shfl_xor(pmax, 32, 64));

    const bool no_rescale = (pmax <= m_run);
    const float m_new = fmaxf(m_run, pmax);
    const float fac = __builtin_amdgcn_exp2f(m_run - m_new);
    float rsum = 0.f;
    #pragma unroll
    for (int r = 0; r < 16; ++r) {
      st0[r] = __builtin_amdgcn_exp2f(st0[r] - m_new);
      st1[r] = __builtin_amdgcn_exp2f(st1[r] - m_new);
      rsum += st0[r] + st1[r];
    }
    rsum += __shfl_xor(rsum, 32, 64);
    l_run = l_run * fac + rsum;
    m_run = m_new;

    if (!__all(no_rescale)) {
      #pragma unroll
      for (int r = 0; r < 16; ++r) {
        float fr = __shfl(fac, (r & 3) + 8 * (r >> 2) + 4 * hi, 64);
        #pragma unroll
        for (int dt = 0; dt < 4; ++dt) of[dt][r] *= fr;
      }
    }

    u32x4 pa[4];
    #pragma unroll
    for (int g = 0; g < 4; ++g) {
      const float* sp = (g < 2) ? (const float*)&st0 : (const float*)&st1;
      const int o8 = (g & 1) * 8;
      u32 a0 = pk2(sp[o8 + 0], sp[o8 + 1]);
      u32 a1 = pk2(sp[o8 + 2], sp[o8 + 3]);
      u32 b0 = pk2(sp[o8 + 4], sp[o8 + 5]);
      u32 b1 = pk2(sp[o8 + 6], sp[o8 + 7]);
      u32 ta0 = __shfl_xor(a0, 32, 64);
      u32 ta1 = __shfl_xor(a1, 32, 64);
      u32 tb0 = __shfl_xor(b0, 32, 64);
      u32 tb1 = __shfl_xor(b1, 32, 64);
      pa[g][0] = hi ? tb0 : a0;
      pa[g][1] = hi ? tb1 : a1;
      pa[g][2] = hi ? b0  : ta0;
      pa[g][3] = hi ? b1  : ta1;
    }

    #pragma unroll
    for (int ks = 0; ks < 4; ++ks) {
      bf16x8 paf = __builtin_bit_cast(bf16x8, pa[ks]);
      #pragma unroll
      for (int dt = 0; dt < 4; ++dt)
        of[dt] = __builtin_amdgcn_mfma_f32_32x32x16_bf16(paf, vfr[dt][ks], of[dt], 0, 0, 0);
    }
  }

  // ---- merge partials (flash combine) ----
  if (w == 1) {
    #pragma unroll
    for (int dt = 0; dt < 4; ++dt)
      #pragma unroll
      for (int r = 0; r < 16; ++r)
        ofs[dt * 16 + r][lane] = of[dt][r];
    mls[0][lane] = m_run;
    mls[1][lane] = l_run;
  }
  __syncthreads();
  if (w == 0) {
    const float m1 = mls[0][l31];
    const float l1 = mls[1][l31];
    const float mt = fmaxf(m_run, m1);
    const float f0 = __builtin_amdgcn_exp2f(m_run - mt);
    const float f1 = __builtin_amdgcn_exp2f(m1 - mt);
    const float lt = l_run * f0 + l1 * f1;
    const float rl = 1.0f / lt;
    #pragma unroll
    for (int r = 0; r < 16; ++r) {
      int crow = (r & 3) + 8 * (r >> 2) + 4 * hi;
      float f0r = __shfl(f0, crow, 64);
      float f1r = __shfl(f1, crow, 64);
      float lr  = __shfl(rl, crow, 64);
      #pragma unroll
      for (int dt = 0; dt < 4; ++dt)
        out[((size_t)(bb * NT + q0 + crow)) * ND + dt * 32 + l31] =
            (of[dt][r] * f0r + ofs[dt * 16 + r][lane] * f1r) * lr;
    }
  }
}

extern "C" void kernel_launch(void* const* d_in, const int* in_sizes, int n_in,
                              void* d_out, int out_size, void* d_ws, size_t ws_size,
                              hipStream_t stream) {
  (void)in_sizes; (void)n_in; (void)out_size; (void)ws_size;
  const float* x  = (const float*)d_in[0];
  const float* Wq = (const float*)d_in[1];
  const float* Wk = (const float*)d_in[2];
  const float* Wv = (const float*)d_in[3];
  float* out = (float*)d_out;

  u16* qws = (u16*)d_ws;                                // frag-order q: 8 MB
  u16* kws = qws + (size_t)NB * NT * ND;                // frag-order k: 8 MB
  u16* vws = kws + (size_t)NB * NT * ND;                // frag-order v: 8 MB
  u16* wfs = vws + (size_t)NB * NT * ND;                // frag-order W: 768 KB

  wprep_k<<<dim3(12), dim3(256), 0, stream>>>(Wq, Wk, Wv, wfs);
  qkv_fused_k<<<dim3(512), dim3(512), 0, stream>>>(x, wfs, qws, kws, vws);
  attn_fwd_k<<<dim3(1024), dim3(128), 0, stream>>>(qws, kws, vws, out);
}

// Round 8
// 102.519 us; speedup vs baseline: 2.2901x; 1.1614x over previous
//
#include <hip/hip_runtime.h>

typedef unsigned short u16;
typedef unsigned int   u32;
typedef __attribute__((ext_vector_type(8)))  __bf16 bf16x8;
typedef __attribute__((ext_vector_type(16))) float  f32x16;
typedef __attribute__((ext_vector_type(4)))  float  fl4;
typedef __attribute__((ext_vector_type(4)))  u16    u16x4;
typedef __attribute__((ext_vector_type(4)))  u32    u32x4;

#define NB 16
#define NT 2048
#define NC 1024
#define ND 128

// Fragment-order layouts:
//   q/k per batch: [t32 0..63][ds 0..7][lane][8]  (1KB per (t32,ds))
//   v  per batch: [c=t>>4 0..127][dt=d>>5 0..3][lane=(d&31)+32*((t>>3)&1)][j=t&7]
//   wf: [cb 0..11][ks 0..63][lane][8] : W_{cb>>2}[k=ks*16+(lane>>5)*8+j][(cb&3)*32+(lane&31)]

__device__ __forceinline__ u16 f2bf(float f) {
  u32 u = __builtin_bit_cast(u32, f);
  u = (u + 0x7fffu + ((u >> 16) & 1u)) >> 16;
  return (u16)u;
}

__device__ __forceinline__ u32 pk2(float lo, float hi) {
  return (u32)f2bf(lo) | ((u32)f2bf(hi) << 16);
}

// -------------------- Kernel 0: W -> fragment-order wf --------------------
__global__ __launch_bounds__(256) void wprep_k(
    const float* __restrict__ Wq, const float* __restrict__ Wk,
    const float* __restrict__ Wv, u16* __restrict__ wf)
{
  const int cb   = blockIdx.x;          // 0..11
  const int kind = cb >> 2;
  const float* __restrict__ W = (kind == 0) ? Wq : (kind == 1) ? Wk : Wv;
  const int lane = threadIdx.x & 63;
  const int ksq  = threadIdx.x >> 6;    // 0..3
  const int l31 = lane & 31, hi = lane >> 5;
  const int d = (cb & 3) * 32 + l31;
  u16* __restrict__ o = wf + (size_t)cb * 64 * 512;
  #pragma unroll 4
  for (int ii = 0; ii < 16; ++ii) {
    int ks = ksq * 16 + ii;
    int k  = ks * 16 + hi * 8;
    u16x4 p0, p1;
    #pragma unroll
    for (int j = 0; j < 4; ++j) p0[j] = f2bf(W[(size_t)(k + j) * ND + d]);
    #pragma unroll
    for (int j = 0; j < 4; ++j) p1[j] = f2bf(W[(size_t)(k + 4 + j) * ND + d]);
    u16* dst = o + ((size_t)ks * 64 + lane) * 8;
    *(u16x4*)dst = p0;
    *(u16x4*)(dst + 4) = p1;
  }
}

// -------------------- Kernel 1: fused QKV projection --------------------
// 512 blocks (128 rows x 192-col half) x 512 thr (8 waves = 4r x 2c).
// A: coalesced x loads (16 lanes/row), XOR-swizzled row-major LDS, 2-deep
// register prefetch (HBM latency). B: frag-order contiguous wf loads (L2),
// 1-deep prefetch. Double-buffered LDS, 1 barrier/K-step.
__global__ __launch_bounds__(512, 4) void qkv_fused_k(
    const float* __restrict__ x, const u16* __restrict__ wf,
    u16* __restrict__ qf, u16* __restrict__ kf, u16* __restrict__ vf)
{
  const int blk  = blockIdx.x;          // 0..511
  const int brow = blk >> 1;            // 128-row tile (adjacent blks share -> L2)
  const int h    = blk & 1;             // 192-col half
  const int tid  = threadIdx.x;
  const int lane = tid & 63;
  const int wid  = tid >> 6;            // 0..7
  const int rw = wid & 3, cw = wid >> 2;
  const int l31 = lane & 31, hi = lane >> 5;
  const int m0 = brow * 128;
  const int cbg0 = h * 6;

  __shared__ u16 Ab[2][128 * 64];       // row-major bf16: byte=row*128+((2c)^((row&7)<<4))
  __shared__ u16 Bb[2][24 * 512];       // frag-order: addr16B = (cb6*4+ks)*64+lane

  // A staging: coalesced — row = tid>>4 (+p*32), f32 col = (tid&15)*4
  const int arow = tid >> 4;            // 0..31
  const int ac4  = (tid & 15) * 4;
  const float* __restrict__ xr = x + (size_t)(m0 + arow) * NC + ac4;

  fl4 pA0[4], pA1[4];                   // 2-deep pending A (f32)
  bf16x8 pb[3];                         // 1-deep pending B

  auto issueA = [&](fl4* dst, int bk) {
    #pragma unroll
    for (int p = 0; p < 4; ++p)
      dst[p] = *(const fl4*)(xr + (size_t)p * 32 * NC + bk * 64);
  };
  auto issueB = [&](int bk) {
    #pragma unroll
    for (int i = 0; i < 3; ++i) {
      int idx = i * 512 + tid;
      int cb6 = idx >> 8, ks = (idx >> 6) & 3;
      pb[i] = *(const bf16x8*)(wf + (((size_t)(cbg0 + cb6) * 64 + bk * 4 + ks) * 64 + (idx & 63)) * 8);
    }
  };
  auto writeA = [&](int buf, fl4* src) {
    char* b = (char*)Ab[buf];
    #pragma unroll
    for (int p = 0; p < 4; ++p) {
      int row = p * 32 + arow;
      u16x4 pk;
      pk[0] = f2bf(src[p][0]); pk[1] = f2bf(src[p][1]);
      pk[2] = f2bf(src[p][2]); pk[3] = f2bf(src[p][3]);
      *(u16x4*)(b + row * 128 + ((ac4 * 2) ^ ((row & 7) << 4))) = pk;
    }
  };
  auto writeB = [&](int buf) {
    #pragma unroll
    for (int i = 0; i < 3; ++i)
      *(bf16x8*)&Bb[buf][((size_t)i * 512 + tid) * 8] = pb[i];
  };

  f32x16 acc[3] = {};

  auto compute = [&](int buf) {
    const char* ab = (const char*)Ab[buf];
    #pragma unroll
    for (int ks = 0; ks < 4; ++ks) {
      int row = rw * 32 + l31;
      bf16x8 a = *(const bf16x8*)(ab + row * 128 + ((ks * 32 + hi * 16) ^ ((row & 7) << 4)));
      #pragma unroll
      for (int cb = 0; cb < 3; ++cb) {
        bf16x8 b = *(const bf16x8*)&Bb[buf][((size_t)((cw * 3 + cb) * 4 + ks) * 64 + lane) * 8];
        acc[cb] = __builtin_amdgcn_mfma_f32_32x32x16_bf16(a, b, acc[cb], 0, 0, 0);
      }
    }
  };

  auto ITER = [&](int bk, fl4* sFill, fl4* sNext) {
    if (bk + 2 < 16) issueA(sFill, bk + 2);
    if (bk + 1 < 16) issueB(bk + 1);
    compute(bk & 1);
    if (bk + 1 < 16) { writeA((bk + 1) & 1, sNext); writeB((bk + 1) & 1); }
    __syncthreads();
  };

  issueA(pA0, 0); issueA(pA1, 1); issueB(0);
  writeA(0, pA0); writeB(0);
  __syncthreads();

  #pragma unroll
  for (int i = 0; i < 8; ++i) {
    ITER(2 * i,     pA0, pA1);
    ITER(2 * i + 1, pA1, pA0);
  }

  // ---- epilogue: frag-order q/k/v writes ----
  const int t32 = brow * 4 + rw;
  #pragma unroll
  for (int cb = 0; cb < 3; ++cb) {
    const int colb = h * 192 + cw * 96 + cb * 32;  // wave-uniform
    const int kind = colb >> 7;
    const int d    = (colb & 127) + l31;
    if (kind < 2) {
      u16* __restrict__ o = kind ? kf : qf;
      const float sc = kind ? 1.0f : 0.12752539240377073f; // log2e/sqrt(128)
      const int ds = d >> 4, b3 = (d >> 3) & 1, j = d & 7;
      u16* __restrict__ base = o + ((size_t)t32 * 8 + ds) * 512 + 32 * b3 * 8 + j;
      #pragma unroll
      for (int r = 0; r < 16; ++r) {
        int crow = (r & 3) + 8 * (r >> 2) + 4 * hi;
        base[crow * 8] = f2bf(acc[cb][r] * sc);
      }
    } else {
      const int dt = (d & 127) >> 5;
      #pragma unroll
      for (int g = 0; g < 4; ++g) {
        int c16   = t32 * 2 + (g >> 1);
        int lanep = l31 + 32 * (g & 1);
        u16x4 pk;
        #pragma unroll
        for (int jj = 0; jj < 4; ++jj) pk[jj] = f2bf(acc[cb][g * 4 + jj]);
        *(u16x4*)(vf + (((size_t)c16 * 4 + dt) * 64 + lanep) * 8 + 4 * hi) = pk;
      }
    }
  }
}

// -------------------- Kernel 2: flash attention (KV-split x2) --------------------
// 1024 blocks x 2 waves; both waves share one (batch, 32-row q-tile), wave w
// handles kv steps s == w (mod 2). Partials merged via LDS (flash combine).
__global__ __launch_bounds__(128, 2) void attn_fwd_k(
    const u16* __restrict__ qw, const u16* __restrict__ kw,
    const u16* __restrict__ vw, float* __restrict__ out)
{
  const int tid  = threadIdx.x;
  const int lane = tid & 63;
  const int w    = tid >> 6;            // 0/1 split
  const int l31  = lane & 31;
  const int hi   = lane >> 5;

  const int c  = blockIdx.x;
  const int bb = (c >> 6) & 15;
  const int qi = ((c & 63) + ((c >> 8) << 4)) & 63;
  const int q0 = qi * 32;
  const int qrow = q0 + l31;

  const u16* __restrict__ qb = qw + ((size_t)bb * 64 + qi) * 4096;
  const u16* __restrict__ kb = kw + (size_t)bb * 64 * 4096;
  const u16* __restrict__ vb = vw + (size_t)bb * 128 * 2048;

  __shared__ float ofs[64][64];         // [dt*16+r][lane]
  __shared__ float mls[2][64];

  bf16x8 qfr[8];
  #pragma unroll
  for (int s = 0; s < 8; ++s)
    qfr[s] = *(const bf16x8*)(qb + ((size_t)s * 64 + lane) * 8);

  f32x16 of[4] = {};
  float m_run = -__builtin_inff();
  float l_run = 0.f;

  const int nsteps = (qi >> 1) + 1;
  for (int s = w; s < nsteps; s += 2) {
    const int kv0 = s * 64;
    const bool masked = (s == nsteps - 1);

    bf16x8 kf0[8], kf1[8];
    #pragma unroll
    for (int t = 0; t < 8; ++t) {
      kf0[t] = *(const bf16x8*)(kb + (((size_t)(2 * s) * 8 + t) * 64 + lane) * 8);
      kf1[t] = *(const bf16x8*)(kb + (((size_t)(2 * s + 1) * 8 + t) * 64 + lane) * 8);
    }
    f32x16 st0 = {}, st1 = {};
    #pragma unroll
    for (int t = 0; t < 8; ++t) {
      st0 = __builtin_amdgcn_mfma_f32_32x32x16_bf16(kf0[t], qfr[t], st0, 0, 0, 0);
      st1 = __builtin_amdgcn_mfma_f32_32x32x16_bf16(kf1[t], qfr[t], st1, 0, 0, 0);
    }
    bf16x8 vfr[4][4];
    #pragma unroll
    for (int ks = 0; ks < 4; ++ks)
      #pragma unroll
      for (int dt = 0; dt < 4; ++dt)
        vfr[dt][ks] = *(const bf16x8*)(vb + (((size_t)((kv0 >> 4) + ks) * 4 + dt) * 64 + lane) * 8);

    if (masked) {
      #pragma unroll
      for (int r = 0; r < 16; ++r) {
        int crow = (r & 3) + 8 * (r >> 2) + 4 * hi;
        st0[r] = (kv0 + crow      <= qrow) ? st0[r] : -1e30f;
        st1[r] = (kv0 + 32 + crow <= qrow) ? st1[r] : -1e30f;
      }
    }

    float pmax = -1e30f;
    #pragma unroll
    for (int r = 0; r < 16; ++r) pmax = fmaxf(pmax, fmaxf(st0[r], st1[r]));
    pmax = fmaxf(pmax, __shfl_xor(pmax, 32, 64));

    const bool no_rescale = (pmax <= m_run);
    const float m_new = fmaxf(m_run, pmax);
    const float fac = __builtin_amdgcn_exp2f(m_run - m_new);
    float rsum = 0.f;
    #pragma unroll
    for (int r = 0; r < 16; ++r) {
      st0[r] = __builtin_amdgcn_exp2f(st0[r] - m_new);
      st1[r] = __builtin_amdgcn_exp2f(st1[r] - m_new);
      rsum += st0[r] + st1[r];
    }
    rsum += __shfl_xor(rsum, 32, 64);
    l_run = l_run * fac + rsum;
    m_run = m_new;

    if (!__all(no_rescale)) {
      #pragma unroll
      for (int r = 0; r < 16; ++r) {
        float fr = __shfl(fac, (r & 3) + 8 * (r >> 2) + 4 * hi, 64);
        #pragma unroll
        for (int dt = 0; dt < 4; ++dt) of[dt][r] *= fr;
      }
    }

    u32x4 pa[4];
    #pragma unroll
    for (int g = 0; g < 4; ++g) {
      const float* sp = (g < 2) ? (const float*)&st0 : (const float*)&st1;
      const int o8 = (g & 1) * 8;
      u32 a0 = pk2(sp[o8 + 0], sp[o8 + 1]);
      u32 a1 = pk2(sp[o8 + 2], sp[o8 + 3]);
      u32 b0 = pk2(sp[o8 + 4], sp[o8 + 5]);
      u32 b1 = pk2(sp[o8 + 6], sp[o8 + 7]);
      u32 ta0 = __shfl_xor(a0, 32, 64);
      u32 ta1 = __shfl_xor(a1, 32, 64);
      u32 tb0 = __shfl_xor(b0, 32, 64);
      u32 tb1 = __shfl_xor(b1, 32, 64);
      pa[g][0] = hi ? tb0 : a0;
      pa[g][1] = hi ? tb1 : a1;
      pa[g][2] = hi ? b0  : ta0;
      pa[g][3] = hi ? b1  : ta1;
    }

    #pragma unroll
    for (int ks = 0; ks < 4; ++ks) {
      bf16x8 paf = __builtin_bit_cast(bf16x8, pa[ks]);
      #pragma unroll
      for (int dt = 0; dt < 4; ++dt)
        of[dt] = __builtin_amdgcn_mfma_f32_32x32x16_bf16(paf, vfr[dt][ks], of[dt], 0, 0, 0);
    }
  }

  if (w == 1) {
    #pragma unroll
    for (int dt = 0; dt < 4; ++dt)
      #pragma unroll
      for (int r = 0; r < 16; ++r)
        ofs[dt * 16 + r][lane] = of[dt][r];
    mls[0][lane] = m_run;
    mls[1][lane] = l_run;
  }
  __syncthreads();
  if (w == 0) {
    const float m1 = mls[0][l31];
    const float l1 = mls[1][l31];
    const float mt = fmaxf(m_run, m1);
    const float f0 = __builtin_amdgcn_exp2f(m_run - mt);
    const float f1 = __builtin_amdgcn_exp2f(m1 - mt);
    const float lt = l_run * f0 + l1 * f1;
    const float rl = 1.0f / lt;
    #pragma unroll
    for (int r = 0; r < 16; ++r) {
      int crow = (r & 3) + 8 * (r >> 2) + 4 * hi;
      float f0r = __shfl(f0, crow, 64);
      float f1r = __shfl(f1, crow, 64);
      float lr  = __shfl(rl, crow, 64);
      #pragma unroll
      for (int dt = 0; dt < 4; ++dt)
        out[((size_t)(bb * NT + q0 + crow)) * ND + dt * 32 + l31] =
            (of[dt][r] * f0r + ofs[dt * 16 + r][lane] * f1r) * lr;
    }
  }
}

extern "C" void kernel_launch(void* const* d_in, const int* in_sizes, int n_in,
                              void* d_out, int out_size, void* d_ws, size_t ws_size,
                              hipStream_t stream) {
  (void)in_sizes; (void)n_in; (void)out_size; (void)ws_size;
  const float* x  = (const float*)d_in[0];
  const float* Wq = (const float*)d_in[1];
  const float* Wk = (const float*)d_in[2];
  const float* Wv = (const float*)d_in[3];
  float* out = (float*)d_out;

  u16* qws = (u16*)d_ws;                                // frag-order q: 8 MB
  u16* kws = qws + (size_t)NB * NT * ND;                // frag-order k: 8 MB
  u16* vws = kws + (size_t)NB * NT * ND;                // frag-order v: 8 MB
  u16* wfs = vws + (size_t)NB * NT * ND;                // frag-order W: 768 KB

  wprep_k<<<dim3(12), dim3(256), 0, stream>>>(Wq, Wk, Wv, wfs);
  qkv_fused_k<<<dim3(512), dim3(512), 0, stream>>>(x, wfs, qws, kws, vws);
  attn_fwd_k<<<dim3(1024), dim3(128), 0, stream>>>(qws, kws, vws, out);
}